// Round 7
// baseline (137.082 us; speedup 1.0000x reference)
//
#include <hip/hip_runtime.h>
#include <cstdint>

#define NV 200000
#define NCOLS 5
#define P 128
#define NE 8192
#define NC 1024
#define EPB 4      // edges per block (grid = NE/EPB)
#define KROW 24    // shorts per frag row: 16 slots + 8 pad = 48B (16B-aligned, 12-bank stride -> 2-way = free)

typedef _Float16 half8 __attribute__((ext_vector_type(8)));
typedef float   float4v __attribute__((ext_vector_type(4)));

// ---------------- Kernel 1: gather dense coords + global max coord^2 ----------------
__global__ __launch_bounds__(256) void gather_kernel(
    const float* __restrict__ data,
    const int*   __restrict__ clusts,
    float4*      __restrict__ dense,
    int*         __restrict__ b2max)
{
    const int idx = blockIdx.x * 256 + threadIdx.x;   // 0 .. NC*P-1
    const int v = clusts[idx];
    const float x = data[v * NCOLS + 1];
    const float y = data[v * NCOLS + 2];
    const float z = data[v * NCOLS + 3];
    dense[idx] = make_float4(x, y, z, 0.f);

    // global max coord^2 (rigorous filter margin); ws poison 0xAAAAAAAA is a
    // large negative int, so int atomicMax with positive-float bits works.
    float mm = fmaxf(fmaxf(x * x, y * y), z * z);
    for (int off = 32; off > 0; off >>= 1)
        mm = fmaxf(mm, __shfl_down(mm, off, 64));
    if ((threadIdx.x & 63) == 0) atomicMax(b2max, __float_as_int(mm));
}

// ---------------- Kernel 2: 4 edges/block, fused build, MFMA filter, wave-local exact rescore ----
// fp16-split distance matmul, K-slot pairing (sum_k A[i,k]*B[k,j] ~= |a|^2+|b|^2-2a.b):
//   A row: [xh yh zh xl yl zl xh yh | zh s2h s2l 1 1 0 0 0]   (k16..31 -> zero page)
//   B row: [-2xh -2yh -2zh -2xh -2yh -2zh -2xl -2yl | -2zl 1 1 s2h s2l 0 0 0]
__global__ __launch_bounds__(256) void edge_kernel(
    const float4* __restrict__ dense,
    const int*    __restrict__ edge_index,
    const float*  __restrict__ b2max,
    float*        __restrict__ out)
{
    #pragma clang fp contract(off)   // exact path must match reference rounding

    const int t = threadIdx.x;
    const int b = blockIdx.x;

    __shared__ float4 x1s[P];                          // 2 KB
    __shared__ float4 x2s[P];                          // 2 KB
    __shared__ alignas(16) _Float16 sA[P * KROW];      // 6 KB
    __shared__ alignas(16) _Float16 sB[P * KROW];      // 6 KB
    __shared__ alignas(16) _Float16 zp[16];            // broadcast zero page for MFMA quads 2,3
    __shared__ unsigned long long wmin[4];

    if (t < 16) zp[t] = (_Float16)0.f;   // published by iter-0's first barrier

    const float B2 = *b2max;
    // wave-local-tau margin must be 2E (E = fp16-split err bound ~1.5e-4*B2 + denorm slack)
    const float margin = 2.0f * (1.5e-4f * B2 + 8.0e-3f);

    int c1a[EPB], c2a[EPB];
    #pragma unroll
    for (int k = 0; k < EPB; ++k) {
        c1a[k] = edge_index[b * EPB + k];
        c2a[k] = edge_index[NE + b * EPB + k];
    }

    const bool isA = (t < P);
    const int  p   = isA ? t : (t - P);
    const int lane = t & 63, w = t >> 6, m = lane & 15, quad = lane >> 4;

    // initial coalesced prefetch (edge 0)
    float4 pf = dense[(isA ? c1a[0] : c2a[0]) * P + p];

    for (int ee = 0; ee < EPB; ++ee) {
        // ---- publish coords + build own frag row (no barrier needed in between) ----
        const float4 c = pf;
        if (isA) x1s[p] = c; else x2s[p] = c;
        {
            const float x = c.x, y = c.y, z = c.z;
            const _Float16 xh = (_Float16)x, yh = (_Float16)y, zh = (_Float16)z;
            const _Float16 xl = (_Float16)(x - (float)xh);
            const _Float16 yl = (_Float16)(y - (float)yh);
            const _Float16 zl = (_Float16)(z - (float)zh);
            const float s2 = x * x + y * y + z * z;
            const _Float16 s2h = (_Float16)s2;
            const _Float16 s2l = (_Float16)(s2 - (float)s2h);
            const _Float16 one = (_Float16)1.0f;
            const _Float16 zer = (_Float16)0.0f;

            _Float16 row[16];
            if (isA) {
                row[0] = xh;  row[1] = yh;   row[2] = zh;   row[3] = xl;
                row[4] = yl;  row[5] = zl;   row[6] = xh;   row[7] = yh;
                row[8] = zh;  row[9] = s2h;  row[10] = s2l; row[11] = one;
                row[12] = one; row[13] = zer; row[14] = zer; row[15] = zer;
            } else {
                const _Float16 n2 = (_Float16)(-2.0f);
                const _Float16 m2xh = n2 * xh, m2yh = n2 * yh, m2zh = n2 * zh; // exact (x2)
                const _Float16 m2xl = n2 * xl, m2yl = n2 * yl, m2zl = n2 * zl;
                row[0] = m2xh; row[1] = m2yh; row[2] = m2zh; row[3] = m2xh;
                row[4] = m2yh; row[5] = m2zh; row[6] = m2xl; row[7] = m2yl;
                row[8] = m2zl; row[9] = one;  row[10] = one; row[11] = s2h;
                row[12] = s2l; row[13] = zer; row[14] = zer; row[15] = zer;
            }
            ulonglong2* dst = (ulonglong2*)&(isA ? sA : sB)[p * KROW];  // 48B rows, 16B-aligned
            const ulonglong2* src = (const ulonglong2*)row;
            dst[0] = src[0]; dst[1] = src[1];
        }
        __syncthreads();   // frags + coords visible block-wide

        // ---- software pipeline: prefetch next edge's coords during compute ----
        if (ee + 1 < EPB)
            pf = dense[(isA ? c1a[ee + 1] : c2a[ee + 1]) * P + p];

        // ---- MFMA filter: wave w owns A-rows [32w,32w+32) as two 16-row tiles ----
        const _Float16* a0p = (quad < 2) ? &sA[(w * 32 +      m) * KROW + quad * 8] : zp;
        const _Float16* a1p = (quad < 2) ? &sA[(w * 32 + 16 + m) * KROW + quad * 8] : zp;
        const half8 a0 = *(const half8*)a0p;
        const half8 a1 = *(const half8*)a1p;

        float4v acc[2][8];
        #pragma unroll
        for (int tr = 0; tr < 2; ++tr)
            #pragma unroll
            for (int tc = 0; tc < 8; ++tc)
                acc[tr][tc] = (float4v){0.f, 0.f, 0.f, 0.f};

        #pragma unroll
        for (int tc = 0; tc < 8; ++tc) {
            const _Float16* bp = (quad < 2) ? &sB[(tc * 16 + m) * KROW + quad * 8] : zp;
            const half8 bb = *(const half8*)bp;
            acc[0][tc] = __builtin_amdgcn_mfma_f32_16x16x32_f16(a0, bb, acc[0][tc], 0, 0, 0);
            acc[1][tc] = __builtin_amdgcn_mfma_f32_16x16x32_f16(a1, bb, acc[1][tc], 0, 0, 0);
        }

        // ---- per-tile / per-lane min, wave-local reduce, wave-local tau ----
        float tmin[16];
        #pragma unroll
        for (int tr = 0; tr < 2; ++tr)
            #pragma unroll
            for (int tc = 0; tc < 8; ++tc) {
                const float4v vv = acc[tr][tc];
                tmin[tr * 8 + tc] = fminf(fminf(vv.x, vv.y), fminf(vv.z, vv.w));
            }
        float red = tmin[0];
        #pragma unroll
        for (int k = 1; k < 16; ++k) red = fminf(red, tmin[k]);
        for (int off = 32; off > 0; off >>= 1)
            red = fminf(red, __shfl_down(red, off, 64));
        const float tauw = __shfl(red, 0, 64) + margin;

        // ---- exact rescore of wave-local candidates (reference rounding + tie-break) ----
        unsigned long long bestkey = ~0ull;
        #pragma unroll
        for (int tr = 0; tr < 2; ++tr) {
            #pragma unroll
            for (int tc = 0; tc < 8; ++tc) {
                if (tmin[tr * 8 + tc] <= tauw) {
                    const float4v vv = acc[tr][tc];
                    #pragma unroll
                    for (int r = 0; r < 4; ++r) {
                        const float sv = (r == 0) ? vv.x : (r == 1) ? vv.y : (r == 2) ? vv.z : vv.w;
                        if (sv <= tauw) {
                            // C/D layout: col = lane&15, row = quad*4 + r
                            const int i = w * 32 + tr * 16 + quad * 4 + r;
                            const int j = tc * 16 + m;
                            const float4 pa = x1s[i];
                            const float4 pb = x2s[j];
                            const float dx = __fsub_rn(pa.x, pb.x);
                            const float dy = __fsub_rn(pa.y, pb.y);
                            const float dz = __fsub_rn(pa.z, pb.z);
                            const float d2 = __fadd_rn(
                                __fadd_rn(__fmul_rn(dx, dx), __fmul_rn(dy, dy)),
                                __fmul_rn(dz, dz));
                            const unsigned long long key =
                                ((unsigned long long)__float_as_uint(d2) << 32) |
                                (unsigned)(i * P + j);
                            if (key < bestkey) bestkey = key;
                        }
                    }
                }
            }
        }

        for (int off = 32; off > 0; off >>= 1) {
            unsigned long long other = __shfl_down(bestkey, off, 64);
            if (other < bestkey) bestkey = other;
        }
        if (lane == 0) wmin[w] = bestkey;
        __syncthreads();

        // ---- epilogue (thread 0) ----
        if (t == 0) {
            unsigned long long k0 = wmin[0];
            #pragma unroll
            for (int q = 1; q < 4; ++q) if (wmin[q] < k0) k0 = wmin[q];
            const int flat = (int)(k0 & 0xffffffffull);
            const int i1 = flat >> 7;
            const int i2 = flat & (P - 1);

            const float v1x = x1s[i1].x, v1y = x1s[i1].y, v1z = x1s[i1].z;
            const float v2x = x2s[i2].x, v2y = x2s[i2].y, v2z = x2s[i2].z;

            const float dx = v1x - v2x, dy = v1y - v2y, dz = v1z - v2z;
            const float lend = sqrtf(dx * dx + dy * dy + dz * dz);

            float nx, ny, nz;
            if (lend > 0.f) { nx = dx / lend; ny = dy / lend; nz = dz / lend; }
            else            { nx = dx;        ny = dy;        nz = dz;        }

            const float B[9] = { nx*nx, nx*ny, nx*nz,
                                 ny*nx, ny*ny, ny*nz,
                                 nz*nx, nz*ny, nz*nz };

            float* o = out + (size_t)(b * EPB + ee) * 38;
            o[0] = v1x; o[1] = v1y; o[2] = v1z;
            o[3] = v2x; o[4] = v2y; o[5] = v2z;
            o[6] = nx;  o[7] = ny;  o[8] = nz;  o[9] = lend;
            #pragma unroll
            for (int q = 0; q < 9; ++q) o[10 + q] = B[q];
            o[19] = v2x; o[20] = v2y; o[21] = v2z;
            o[22] = v1x; o[23] = v1y; o[24] = v1z;
            o[25] = -nx; o[26] = -ny; o[27] = -nz; o[28] = lend;
            #pragma unroll
            for (int q = 0; q < 9; ++q) o[29 + q] = B[q];
        }
        __syncthreads();   // LDS free before next iteration's writes
    }
}

// ---------------- Fallback (ws too small): exact VALU kernel ----------------
__global__ __launch_bounds__(256) void exact_kernel(
    const float* __restrict__ data,
    const int*   __restrict__ clusts,
    const int*   __restrict__ edge_index,
    float*       __restrict__ out)
{
    #pragma clang fp contract(off)
    const int e = blockIdx.x;
    const int t = threadIdx.x;
    __shared__ float4 x1s[P];
    __shared__ float4 x2s[P];
    __shared__ unsigned long long wmin[4];
    const int c1 = edge_index[e];
    const int c2 = edge_index[NE + e];
    if (t < P) {
        const int v = clusts[c1 * P + t];
        x1s[t] = make_float4(data[v*NCOLS+1], data[v*NCOLS+2], data[v*NCOLS+3], 0.f);
    } else {
        const int p = t - P;
        const int v = clusts[c2 * P + p];
        x2s[p] = make_float4(data[v*NCOLS+1], data[v*NCOLS+2], data[v*NCOLS+3], 0.f);
    }
    __syncthreads();
    const int tj = t & 15, ti = t >> 4;
    float4 a[8], b[8];
    #pragma unroll
    for (int k = 0; k < 8; ++k) a[k] = x1s[ti + 16*k];
    #pragma unroll
    for (int mm = 0; mm < 8; ++mm) b[mm] = x2s[tj + 16*mm];
    float bd[8]; int bj[8];
    #pragma unroll
    for (int k = 0; k < 8; ++k) { bd[k] = __builtin_inff(); bj[k] = 0; }
    #pragma unroll
    for (int mm = 0; mm < 8; ++mm) {
        const int j = tj + 16*mm;
        #pragma unroll
        for (int k = 0; k < 8; ++k) {
            const float dx = __fsub_rn(a[k].x, b[mm].x);
            const float dy = __fsub_rn(a[k].y, b[mm].y);
            const float dz = __fsub_rn(a[k].z, b[mm].z);
            const float d2 = __fadd_rn(__fadd_rn(__fmul_rn(dx,dx), __fmul_rn(dy,dy)), __fmul_rn(dz,dz));
            if (d2 < bd[k]) { bd[k] = d2; bj[k] = j; }
        }
    }
    float bestd = __builtin_inff(); int bestflat = 0;
    #pragma unroll
    for (int k = 0; k < 8; ++k)
        if (bd[k] < bestd) { bestd = bd[k]; bestflat = (ti + 16*k) * P + bj[k]; }
    unsigned long long key = ((unsigned long long)__float_as_uint(bestd) << 32) | (unsigned)bestflat;
    for (int off = 32; off > 0; off >>= 1) {
        unsigned long long other = __shfl_down(key, off, 64);
        if (other < key) key = other;
    }
    if ((t & 63) == 0) wmin[t >> 6] = key;
    __syncthreads();
    if (t == 0) {
        unsigned long long k0 = wmin[0];
        #pragma unroll
        for (int q = 1; q < 4; ++q) if (wmin[q] < k0) k0 = wmin[q];
        const int flat = (int)(k0 & 0xffffffffull);
        const int i1 = flat >> 7, i2 = flat & (P - 1);
        const float v1x = x1s[i1].x, v1y = x1s[i1].y, v1z = x1s[i1].z;
        const float v2x = x2s[i2].x, v2y = x2s[i2].y, v2z = x2s[i2].z;
        const float dx = v1x - v2x, dy = v1y - v2y, dz = v1z - v2z;
        const float lend = sqrtf(dx*dx + dy*dy + dz*dz);
        float nx, ny, nz;
        if (lend > 0.f) { nx = dx/lend; ny = dy/lend; nz = dz/lend; }
        else            { nx = dx; ny = dy; nz = dz; }
        const float B[9] = { nx*nx, nx*ny, nx*nz, ny*nx, ny*ny, ny*nz, nz*nx, nz*ny, nz*nz };
        float* o = out + (size_t)e * 38;
        o[0]=v1x; o[1]=v1y; o[2]=v1z; o[3]=v2x; o[4]=v2y; o[5]=v2z;
        o[6]=nx; o[7]=ny; o[8]=nz; o[9]=lend;
        #pragma unroll
        for (int q = 0; q < 9; ++q) o[10+q] = B[q];
        o[19]=v2x; o[20]=v2y; o[21]=v2z; o[22]=v1x; o[23]=v1y; o[24]=v1z;
        o[25]=-nx; o[26]=-ny; o[27]=-nz; o[28]=lend;
        #pragma unroll
        for (int q = 0; q < 9; ++q) o[29+q] = B[q];
    }
}

extern "C" void kernel_launch(void* const* d_in, const int* in_sizes, int n_in,
                              void* d_out, int out_size, void* d_ws, size_t ws_size,
                              hipStream_t stream) {
    const float* data       = (const float*)d_in[0];
    const int*   clusts     = (const int*)d_in[1];
    const int*   edge_index = (const int*)d_in[2];
    float*       out        = (float*)d_out;

    char* wsc = (char*)d_ws;
    const size_t denseOff = 256;
    const size_t denseBytes = (size_t)NC * P * sizeof(float4);   // 2 MB
    const size_t need = denseOff + denseBytes;

    if (ws_size >= need) {
        int*    b2max = (int*)wsc;
        float4* dense = (float4*)(wsc + denseOff);
        gather_kernel<<<(NC * P) / 256, 256, 0, stream>>>(data, clusts, dense, b2max);
        edge_kernel<<<NE / EPB, 256, 0, stream>>>(dense, edge_index, (const float*)b2max, out);
    } else {
        exact_kernel<<<NE, 256, 0, stream>>>(data, clusts, edge_index, out);
    }
}